// Round 2
// 960.398 us; speedup vs baseline: 1.0381x; 1.0381x over previous
//
#include <hip/hip_runtime.h>

// Problem constants (fixed by the reference)
constexpr int Nn = 16384;   // nodes at current level
constexpr int Mm = 8192;    // K of big GEMM
constexpr int Ee = 524288;  // edges
constexpr int Dd = 128;     // feature dim

typedef __attribute__((ext_vector_type(8))) short short8v;
typedef __attribute__((ext_vector_type(4))) short short4v;
typedef __attribute__((ext_vector_type(4))) float float4v;

// f32 -> bf16 round-to-nearest-even (inputs finite; no NaN handling needed)
static __device__ __forceinline__ short f2bf(float f) {
    unsigned u = __builtin_bit_cast(unsigned, f);
    u += 0x7fffu + ((u >> 16) & 1u);
    return (short)(u >> 16);
}

// ---------------------------------------------------------------------------
// CSR build + degrees
// ---------------------------------------------------------------------------
__global__ void k_zero_i(int* __restrict__ p, int n) {
    int i = blockIdx.x * 256 + threadIdx.x;
    if (i < n) p[i] = 0;
}

__global__ void k_deg_count(const int* __restrict__ src, const int* __restrict__ dst,
                            int* __restrict__ cnt_out, int* __restrict__ cnt_in) {
    int e = blockIdx.x * 256 + threadIdx.x;
    if (e < Ee) {
        atomicAdd(&cnt_out[src[e]], 1);
        atomicAdd(&cnt_in[dst[e]], 1);
    }
}

__global__ void k_deg_fin(const int* __restrict__ cnt_out, const int* __restrict__ cnt_in,
                          float* __restrict__ rs_out, float* __restrict__ rs_in) {
    int i = blockIdx.x * 256 + threadIdx.x;
    if (i < Nn) {
        rs_out[i] = rsqrtf((float)(cnt_out[i] + 1));   // +1 self-loop
        rs_in[i]  = rsqrtf((float)(cnt_in[i] + 1));
    }
}

// Exclusive prefix sum of cnt[16384] -> row_start[16385]. One block, 1024 thr.
__global__ void k_scan(const int* __restrict__ cnt, int* __restrict__ row_start) {
    __shared__ int s[1024];
    int t = threadIdx.x;
    int base = t * 16;
    int local[16];
    int sum = 0;
#pragma unroll
    for (int i = 0; i < 16; i++) { local[i] = cnt[base + i]; sum += local[i]; }
    s[t] = sum;
    __syncthreads();
    for (int off = 1; off < 1024; off <<= 1) {
        int v = (t >= off) ? s[t - off] : 0;
        __syncthreads();
        s[t] += v;
        __syncthreads();
    }
    int run = s[t] - sum;   // exclusive offset for this thread's chunk
#pragma unroll
    for (int i = 0; i < 16; i++) { row_start[base + i] = run; run += local[i]; }
    if (t == 1023) row_start[16384] = s[1023];
}

__global__ void k_fill(const int* __restrict__ src, const int* __restrict__ dst,
                       const int* __restrict__ row_start, int* __restrict__ cursor,
                       int* __restrict__ ebuf) {
    int e = blockIdx.x * 256 + threadIdx.x;
    if (e < Ee) {
        int d = dst[e];
        int pos = atomicAdd(&cursor[d], 1);
        ebuf[row_start[d] + pos] = src[e];
    }
}

// ---------------------------------------------------------------------------
// Weight prep: Wp[256][128]: rows 0..127 = Wc[r][j]*cw[j], 128..255 = Wf[r-128][j]*tw[j]
//              bp[j] = bc[j]*cw[j] + bf[j]*tw[j]
// (folds the post-GEMM column scales into the weights so the two small GEMMs
//  collapse into one K=256 GEMM)
// ---------------------------------------------------------------------------
__global__ void k_prep(const float* __restrict__ Wc, const float* __restrict__ Wf,
                       const float* __restrict__ bc, const float* __restrict__ bf,
                       const float* __restrict__ cw, const float* __restrict__ tw,
                       float* __restrict__ Wp, float* __restrict__ bp) {
    int i = blockIdx.x * 256 + threadIdx.x;   // 0 .. 32767
    int r = i >> 7, j = i & 127;
    float w = (r < 128) ? Wc[r * 128 + j] * cw[j] : Wf[(r - 128) * 128 + j] * tw[j];
    Wp[i] = w;
    if (i < 128) bp[i] = bc[i] * cw[i] + bf[i] * tw[i];
}

// ---------------------------------------------------------------------------
// Fused dual aggregation: one pass over the edges computes BOTH graph-conv
// aggregations (curr_h path and fused/top-down path). One wave per dst node;
// lane handles 2 features of each matrix.
// agg[d][0:128]   = (sum x1[src]*rs_o[src] + x1[d]*rs_o[d]) * rs_in[d]
// agg[d][128:256] = same over x2
// ---------------------------------------------------------------------------
__global__ void k_agg2(const float* __restrict__ x1, const float* __restrict__ x2,
                       const float* __restrict__ rs_o, const float* __restrict__ rs_i,
                       const int* __restrict__ row_start, const int* __restrict__ ebuf,
                       float* __restrict__ agg) {
    int d = blockIdx.x * 4 + (threadIdx.x >> 6);
    int lane = threadIdx.x & 63;
    int c = lane * 2;
    int beg = row_start[d], end = row_start[d + 1];
    float ax = 0.f, ay = 0.f, bx = 0.f, by = 0.f;
    int i = beg;
    for (; i + 1 < end; i += 2) {   // unroll 2 for load ILP
        int s0 = ebuf[i], s1 = ebuf[i + 1];
        float r0 = rs_o[s0], r1 = rs_o[s1];
        float2 u0 = *(const float2*)(x1 + (size_t)s0 * 128 + c);
        float2 u1 = *(const float2*)(x1 + (size_t)s1 * 128 + c);
        float2 w0 = *(const float2*)(x2 + (size_t)s0 * 128 + c);
        float2 w1 = *(const float2*)(x2 + (size_t)s1 * 128 + c);
        ax += u0.x * r0 + u1.x * r1;
        ay += u0.y * r0 + u1.y * r1;
        bx += w0.x * r0 + w1.x * r1;
        by += w0.y * r0 + w1.y * r1;
    }
    if (i < end) {
        int s0 = ebuf[i];
        float r0 = rs_o[s0];
        float2 u0 = *(const float2*)(x1 + (size_t)s0 * 128 + c);
        float2 w0 = *(const float2*)(x2 + (size_t)s0 * 128 + c);
        ax += u0.x * r0;
        ay += u0.y * r0;
        bx += w0.x * r0;
        by += w0.y * r0;
    }
    float2 us = *(const float2*)(x1 + (size_t)d * 128 + c);
    float2 ws = *(const float2*)(x2 + (size_t)d * 128 + c);
    float ro = rs_o[d], ri = rs_i[d];
    float2 o1, o2;
    o1.x = (ax + us.x * ro) * ri;
    o1.y = (ay + us.y * ro) * ri;
    o2.x = (bx + ws.x * ro) * ri;
    o2.y = (by + ws.y * ro) * ri;
    *(float2*)(agg + (size_t)d * 256 + c) = o1;
    *(float2*)(agg + (size_t)d * 256 + 128 + c) = o2;
}

// ---------------------------------------------------------------------------
// next_h [8192][128] f32 -> Bt [128][8192] bf16 (transpose + convert)
// ---------------------------------------------------------------------------
__global__ void k_bt(const float* __restrict__ B, short* __restrict__ Bt) {
    __shared__ short T[32][40];     // [n_local][k_local], padded
    int kt = blockIdx.x & 255;      // k tile (32 wide)
    int nt = blockIdx.x >> 8;       // n tile (32 wide), 0..3
    int t = threadIdx.x;
    int r = t >> 3;                 // k_local 0..31
    int c4 = (t & 7) * 4;           // n_local 0,4..28
    float4 v = *(const float4*)(B + (size_t)(kt * 32 + r) * 128 + nt * 32 + c4);
    T[c4 + 0][r] = f2bf(v.x);
    T[c4 + 1][r] = f2bf(v.y);
    T[c4 + 2][r] = f2bf(v.z);
    T[c4 + 3][r] = f2bf(v.w);
    __syncthreads();
    int nl = t >> 3, ks = (t & 7) * 4;
    *(short4v*)(Bt + (size_t)(nt * 32 + nl) * 8192 + kt * 32 + ks) =
        *(const short4v*)(&T[nl][ks]);
}

// ---------------------------------------------------------------------------
// Big GEMM via MFMA: fused[16384][128] = curr_inc[16384][8192] @ next_h
// A converted f32->bf16 in-kernel (A read from HBM exactly once).
// Tile: 32 rows x 128 cols, BK=64, 256 threads (4 waves, wave = 32x32 slice).
// 2-deep register prefetch (named A/B sets, no runtime indexing): loads for
// K-step k+2 are issued during step k's MFMA phase -> ~2 phases (~800+ cyc)
// of latency cover before the ds_write's vmcnt consumes them (T14 idiom).
// Verified gfx950 layouts: A-frag A[m=lane&15][k=(lane>>4)*8+j];
//                          C/D col=lane&15, row=(lane>>4)*4+reg.
// ---------------------------------------------------------------------------
__launch_bounds__(256, 2)
__global__ void k_mfma_gemm(const float* __restrict__ A, const short* __restrict__ Bt,
                            float* __restrict__ C) {
    __shared__ short As[32 * 72];    // [m][k], k-stride 72 (pad 8 -> 16B-aligned rows)
    __shared__ short Bs[128 * 72];   // [n][k]

    const int tid = threadIdx.x;
    const int lane = tid & 63;
    const int wv = tid >> 6;         // wave -> 32-col slice
    const int row0 = blockIdx.x * 32;

    // A staging: thread -> row ar, k-segment ak (8 floats -> 8 bf16)
    const int ar = tid >> 3;         // 0..31
    const int ak = (tid & 7) * 8;    // 0..56
    const float* Ap = A + (size_t)(row0 + ar) * Mm + ak;

    // B staging: thread -> n-row bn, k-segment bk (32 bf16 = 4 x short8)
    const int bn = tid >> 1;         // 0..127
    const int bk = (tid & 1) * 32;
    const short* Bp = Bt + (size_t)bn * Mm + bk;

    const int fm = lane & 15;        // fragment row/col
    const int fk = (lane >> 4) * 8;  // fragment k offset

    float4v acc[2][2] = {};

    // prefetch register sets (2-deep pipeline, named to avoid scratch - rule #20)
    float4 a0A, a1A, a0B, a1B;
    short8v b0A, b1A, b2A, b3A, b0B, b1B, b2B, b3B;

#define LOADSET(s, koff)                                   \
    a0##s = *(const float4*)(Ap + (koff));                 \
    a1##s = *(const float4*)(Ap + (koff) + 4);             \
    b0##s = *(const short8v*)(Bp + (koff));                \
    b1##s = *(const short8v*)(Bp + (koff) + 8);            \
    b2##s = *(const short8v*)(Bp + (koff) + 16);           \
    b3##s = *(const short8v*)(Bp + (koff) + 24);

#define PHASE(s, knext)                                                        \
    {                                                                          \
        short8v ap;                                                            \
        ap[0] = f2bf(a0##s.x); ap[1] = f2bf(a0##s.y);                          \
        ap[2] = f2bf(a0##s.z); ap[3] = f2bf(a0##s.w);                          \
        ap[4] = f2bf(a1##s.x); ap[5] = f2bf(a1##s.y);                          \
        ap[6] = f2bf(a1##s.z); ap[7] = f2bf(a1##s.w);                          \
        __syncthreads();                /* prev phase's LDS reads done */      \
        *(short8v*)(&As[ar * 72 + ak]) = ap;                                   \
        *(short8v*)(&Bs[bn * 72 + bk +  0]) = b0##s;                           \
        *(short8v*)(&Bs[bn * 72 + bk +  8]) = b1##s;                           \
        *(short8v*)(&Bs[bn * 72 + bk + 16]) = b2##s;                           \
        *(short8v*)(&Bs[bn * 72 + bk + 24]) = b3##s;                           \
        __syncthreads();                                                       \
        if ((knext) < Mm) { LOADSET(s, knext) }                                \
        _Pragma("unroll")                                                      \
        for (int ks = 0; ks < 2; ks++) {                                       \
            const int kk = ks * 32 + fk;                                       \
            short8v a0f = *(const short8v*)(&As[fm * 72 + kk]);                \
            short8v a1f = *(const short8v*)(&As[(16 + fm) * 72 + kk]);         \
            short8v b0f = *(const short8v*)(&Bs[(wv * 32 + fm) * 72 + kk]);    \
            short8v b1f = *(const short8v*)(&Bs[(wv * 32 + 16 + fm) * 72 + kk]); \
            acc[0][0] = __builtin_amdgcn_mfma_f32_16x16x32_bf16(a0f, b0f, acc[0][0], 0, 0, 0); \
            acc[0][1] = __builtin_amdgcn_mfma_f32_16x16x32_bf16(a0f, b1f, acc[0][1], 0, 0, 0); \
            acc[1][0] = __builtin_amdgcn_mfma_f32_16x16x32_bf16(a1f, b0f, acc[1][0], 0, 0, 0); \
            acc[1][1] = __builtin_amdgcn_mfma_f32_16x16x32_bf16(a1f, b1f, acc[1][1], 0, 0, 0); \
        }                                                                      \
    }

    LOADSET(A, 0)
    LOADSET(B, 64)

    for (int k0 = 0; k0 < Mm; k0 += 128) {
        PHASE(A, k0 + 128)   // computes chunk k0,     reloads set A <- k0+128
        PHASE(B, k0 + 192)   // computes chunk k0+64,  reloads set B <- k0+192
    }
#undef PHASE
#undef LOADSET

    const int crow = (lane >> 4) * 4;
#pragma unroll
    for (int mt = 0; mt < 2; mt++)
#pragma unroll
        for (int nt = 0; nt < 2; nt++)
#pragma unroll
            for (int r = 0; r < 4; r++)
                C[(size_t)(row0 + mt * 16 + crow + r) * 128 + wv * 32 + nt * 16 + fm] =
                    acc[mt][nt][r];
}

// ---------------------------------------------------------------------------
// Small f32 GEMM (K=256) with fused bias + 0.5 mean + LayerNorm + ReLU.
// C[Nn,128] = LN_relu( (A[Nn,256] @ Wp[256,128] + bp) * 0.5 )
// 32-row tile, 256 thr; thread (ty,tx) owns rows ty*4..+3, cols tx*4..+3.
// A row's 128 outputs live in the 32 lanes of one half-wave (same ty) ->
// LN reduce via __shfl_xor masks 16..1 (stays within the 32-lane half).
// ---------------------------------------------------------------------------
__launch_bounds__(256, 2)
__global__ void k_gemm_ln(const float* __restrict__ A, const float* __restrict__ B,
                          const float* __restrict__ bias,
                          const float* __restrict__ gamma, const float* __restrict__ beta,
                          float* __restrict__ out) {
    __shared__ float As[32 * 36];
    __shared__ float Bs[32 * 128];

    const int tid = threadIdx.x;
    const int tx = tid & 31;
    const int ty = tid >> 5;
    const int c4 = tx * 4;
    const int r0 = ty * 4;
    const int row0 = blockIdx.x * 32;

    const int ar = tid >> 3;
    const int ak = (tid & 7) * 4;
    const float* Arow = A + (size_t)(row0 + ar) * 256 + ak;

    float acc[4][4] = {};

    for (int k0 = 0; k0 < 256; k0 += 32) {
        float4 av = *(const float4*)(Arow + k0);
        float4 bv[4];
#pragma unroll
        for (int t = 0; t < 4; t++) {
            int idx = tid + t * 256;
            int br = idx >> 5, bc = (idx & 31) * 4;
            bv[t] = *(const float4*)(B + (size_t)(k0 + br) * 128 + bc);
        }
        __syncthreads();
        As[(ak + 0) * 36 + ar] = av.x;
        As[(ak + 1) * 36 + ar] = av.y;
        As[(ak + 2) * 36 + ar] = av.z;
        As[(ak + 3) * 36 + ar] = av.w;
#pragma unroll
        for (int t = 0; t < 4; t++) {
            int idx = tid + t * 256;
            int br = idx >> 5, bc = (idx & 31) * 4;
            *(float4*)(Bs + br * 128 + bc) = bv[t];
        }
        __syncthreads();
#pragma unroll
        for (int kk = 0; kk < 32; kk++) {
            float4 a4 = *(const float4*)(As + kk * 36 + r0);
            float4 b4 = *(const float4*)(Bs + kk * 128 + c4);
            float a[4] = {a4.x, a4.y, a4.z, a4.w};
            float b[4] = {b4.x, b4.y, b4.z, b4.w};
#pragma unroll
            for (int i = 0; i < 4; i++)
#pragma unroll
                for (int j = 0; j < 4; j++)
                    acc[i][j] = fmaf(a[i], b[j], acc[i][j]);
        }
    }

    float4 bi = *(const float4*)(bias + c4);
    float4 g  = *(const float4*)(gamma + c4);
    float4 be = *(const float4*)(beta + c4);
#pragma unroll
    for (int i = 0; i < 4; i++) {
        float v0 = (acc[i][0] + bi.x) * 0.5f;
        float v1 = (acc[i][1] + bi.y) * 0.5f;
        float v2 = (acc[i][2] + bi.z) * 0.5f;
        float v3 = (acc[i][3] + bi.w) * 0.5f;
        float s1 = v0 + v1 + v2 + v3;
        float s2 = v0 * v0 + v1 * v1 + v2 * v2 + v3 * v3;
#pragma unroll
        for (int m = 16; m >= 1; m >>= 1) {
            s1 += __shfl_xor(s1, m);
            s2 += __shfl_xor(s2, m);
        }
        float mu  = s1 * (1.0f / 128.0f);
        float var = s2 * (1.0f / 128.0f) - mu * mu;
        float inv = rsqrtf(var + 1e-5f);
        float4 o;
        o.x = fmaxf((v0 - mu) * inv * g.x + be.x, 0.0f);
        o.y = fmaxf((v1 - mu) * inv * g.y + be.y, 0.0f);
        o.z = fmaxf((v2 - mu) * inv * g.z + be.z, 0.0f);
        o.w = fmaxf((v3 - mu) * inv * g.w + be.w, 0.0f);
        *(float4*)(out + (size_t)(row0 + r0 + i) * 128 + c4) = o;
    }
}

// ---------------------------------------------------------------------------
extern "C" void kernel_launch(void* const* d_in, const int* in_sizes, int n_in,
                              void* d_out, int out_size, void* d_ws, size_t ws_size,
                              hipStream_t stream) {
    const float* curr_h    = (const float*)d_in[0];
    const float* next_h    = (const float*)d_in[1];
    const float* curr_inc  = (const float*)d_in[2];
    const float* Wc        = (const float*)d_in[3];
    const float* bc        = (const float*)d_in[4];
    const float* Wf        = (const float*)d_in[5];
    const float* bf        = (const float*)d_in[6];
    const float* conv_w    = (const float*)d_in[7];
    const float* topDown_w = (const float*)d_in[8];
    const float* gamma     = (const float*)d_in[9];
    const float* beta      = (const float*)d_in[10];
    const int*   esrc      = (const int*)d_in[11];
    const int*   edst      = (const int*)d_in[12];
    float* out = (float*)d_out;

    // workspace layout (~29 MB)
    char* w = (char*)d_ws;
    int*   cnt_out = (int*)w;    w += (size_t)Nn * 4;
    int*   cnt_in  = (int*)w;    w += (size_t)Nn * 4;
    int*   cursor  = (int*)w;    w += (size_t)Nn * 4;
    int*   row_st  = (int*)w;    w += (size_t)16388 * 4;
    int*   ebuf    = (int*)w;    w += (size_t)Ee * 4;
    float* rs_out  = (float*)w;  w += (size_t)Nn * 4;
    float* rs_in   = (float*)w;  w += (size_t)Nn * 4;
    short* Bt      = (short*)w;  w += (size_t)Dd * Mm * 2;
    float* fused   = (float*)w;  w += (size_t)Nn * Dd * 4;
    float* agg2    = (float*)w;  w += (size_t)Nn * 256 * 4;
    float* Wp      = (float*)w;  w += (size_t)256 * 128 * 4;
    float* bp      = (float*)w;  w += (size_t)1024;

    // CSR + degrees + weight prep (independent of big GEMM)
    k_zero_i<<<(3 * Nn + 255) / 256, 256, 0, stream>>>(cnt_out, 3 * Nn); // cnt_out,cnt_in,cursor contiguous
    k_deg_count<<<Ee / 256, 256, 0, stream>>>(esrc, edst, cnt_out, cnt_in);
    k_deg_fin<<<Nn / 256, 256, 0, stream>>>(cnt_out, cnt_in, rs_out, rs_in);
    k_scan<<<1, 1024, 0, stream>>>(cnt_in, row_st);
    k_fill<<<Ee / 256, 256, 0, stream>>>(esrc, edst, row_st, cursor, ebuf);
    k_prep<<<128, 256, 0, stream>>>(Wc, Wf, bc, bf, conv_w, topDown_w, Wp, bp);

    // B^T bf16, then big MFMA GEMM: fused = curr_inc @ next_h
    k_bt<<<1024, 256, 0, stream>>>(next_h, Bt);
    k_mfma_gemm<<<Nn / 32, 256, 0, stream>>>(curr_inc, Bt, fused);

    // one aggregation pass over both feature stacks, then one fused GEMM+LN
    k_agg2<<<Nn / 4, 256, 0, stream>>>(curr_h, fused, rs_out, rs_in, row_st, ebuf, agg2);
    k_gemm_ln<<<Nn / 32, 256, 0, stream>>>(agg2, Wp, bp, gamma, beta, out);
}

// Round 3
// 928.955 us; speedup vs baseline: 1.0733x; 1.0338x over previous
//
#include <hip/hip_runtime.h>

// Problem constants (fixed by the reference)
constexpr int Nn = 16384;   // nodes at current level
constexpr int Mm = 8192;    // K of big GEMM
constexpr int Ee = 524288;  // edges
constexpr int Dd = 128;     // feature dim

typedef __attribute__((ext_vector_type(8))) short short8v;
typedef __attribute__((ext_vector_type(4))) short short4v;
typedef __attribute__((ext_vector_type(4))) float float4v;

// f32 -> bf16 round-to-nearest-even (inputs finite; no NaN handling needed)
static __device__ __forceinline__ short f2bf(float f) {
    unsigned u = __builtin_bit_cast(unsigned, f);
    u += 0x7fffu + ((u >> 16) & 1u);
    return (short)(u >> 16);
}

// ---------------------------------------------------------------------------
// CSR build + degrees
// ---------------------------------------------------------------------------
__global__ void k_zero_i(int* __restrict__ p, int n) {
    int i = blockIdx.x * 256 + threadIdx.x;
    if (i < n) p[i] = 0;
}

__global__ void k_deg_count(const int* __restrict__ src, const int* __restrict__ dst,
                            int* __restrict__ cnt_out, int* __restrict__ cnt_in) {
    int e = blockIdx.x * 256 + threadIdx.x;
    if (e < Ee) {
        atomicAdd(&cnt_out[src[e]], 1);
        atomicAdd(&cnt_in[dst[e]], 1);
    }
}

__global__ void k_deg_fin(const int* __restrict__ cnt_out, const int* __restrict__ cnt_in,
                          float* __restrict__ rs_out, float* __restrict__ rs_in) {
    int i = blockIdx.x * 256 + threadIdx.x;
    if (i < Nn) {
        rs_out[i] = rsqrtf((float)(cnt_out[i] + 1));   // +1 self-loop
        rs_in[i]  = rsqrtf((float)(cnt_in[i] + 1));
    }
}

// Exclusive prefix sum of cnt[16384] -> row_start[16385]. One block, 1024 thr.
__global__ void k_scan(const int* __restrict__ cnt, int* __restrict__ row_start) {
    __shared__ int s[1024];
    int t = threadIdx.x;
    int base = t * 16;
    int local[16];
    int sum = 0;
#pragma unroll
    for (int i = 0; i < 16; i++) { local[i] = cnt[base + i]; sum += local[i]; }
    s[t] = sum;
    __syncthreads();
    for (int off = 1; off < 1024; off <<= 1) {
        int v = (t >= off) ? s[t - off] : 0;
        __syncthreads();
        s[t] += v;
        __syncthreads();
    }
    int run = s[t] - sum;   // exclusive offset for this thread's chunk
#pragma unroll
    for (int i = 0; i < 16; i++) { row_start[base + i] = run; run += local[i]; }
    if (t == 1023) row_start[16384] = s[1023];
}

__global__ void k_fill(const int* __restrict__ src, const int* __restrict__ dst,
                       const int* __restrict__ row_start, int* __restrict__ cursor,
                       int* __restrict__ ebuf) {
    int e = blockIdx.x * 256 + threadIdx.x;
    if (e < Ee) {
        int d = dst[e];
        int pos = atomicAdd(&cursor[d], 1);
        ebuf[row_start[d] + pos] = src[e];
    }
}

// ---------------------------------------------------------------------------
// Weight prep: Wp[256][128]: rows 0..127 = Wc[r][j]*cw[j], 128..255 = Wf[r-128][j]*tw[j]
//              bp[j] = bc[j]*cw[j] + bf[j]*tw[j]
// ---------------------------------------------------------------------------
__global__ void k_prep(const float* __restrict__ Wc, const float* __restrict__ Wf,
                       const float* __restrict__ bc, const float* __restrict__ bf,
                       const float* __restrict__ cw, const float* __restrict__ tw,
                       float* __restrict__ Wp, float* __restrict__ bp) {
    int i = blockIdx.x * 256 + threadIdx.x;   // 0 .. 32767
    int r = i >> 7, j = i & 127;
    float w = (r < 128) ? Wc[r * 128 + j] * cw[j] : Wf[(r - 128) * 128 + j] * tw[j];
    Wp[i] = w;
    if (i < 128) bp[i] = bc[i] * cw[i] + bf[i] * tw[i];
}

// ---------------------------------------------------------------------------
// next_h [8192][128] f32 -> Bt [128][8192] bf16 (transpose + convert)
// ---------------------------------------------------------------------------
__global__ void k_bt(const float* __restrict__ B, short* __restrict__ Bt) {
    __shared__ short T[32][40];     // [n_local][k_local], padded
    int kt = blockIdx.x & 255;      // k tile (32 wide)
    int nt = blockIdx.x >> 8;       // n tile (32 wide), 0..3
    int t = threadIdx.x;
    int r = t >> 3;                 // k_local 0..31
    int c4 = (t & 7) * 4;           // n_local 0,4..28
    float4 v = *(const float4*)(B + (size_t)(kt * 32 + r) * 128 + nt * 32 + c4);
    T[c4 + 0][r] = f2bf(v.x);
    T[c4 + 1][r] = f2bf(v.y);
    T[c4 + 2][r] = f2bf(v.z);
    T[c4 + 3][r] = f2bf(v.w);
    __syncthreads();
    int nl = t >> 3, ks = (t & 7) * 4;
    *(short4v*)(Bt + (size_t)(nt * 32 + nl) * 8192 + kt * 32 + ks) =
        *(const short4v*)(&T[nl][ks]);
}

// ---------------------------------------------------------------------------
// Big GEMM via MFMA: fused[16384][128] = curr_inc[16384][8192] @ next_h
// Tile: 32 rows x 128 cols, BK=64, 256 threads (4 waves, wave = 32x32 slice).
// 4-deep named register prefetch + RAW barriers (no __syncthreads vmcnt(0)
// drain): loads for phase p+4 issued at phase p; compiler emits *counted*
// vmcnt(N) before first use, so ~3 phases (~1000cy) of HBM cover survive
// across barriers (T3/T4). Raw-barrier pattern per m201 template; rule #18
// sched_barrier fences around barriers.
// ---------------------------------------------------------------------------
__launch_bounds__(256, 2)
__global__ void k_mfma_gemm(const float* __restrict__ A, const short* __restrict__ Bt,
                            float* __restrict__ C) {
    __shared__ short As[32 * 72];    // [m][k], k-stride 72 (pad 8 -> 16B-aligned rows)
    __shared__ short Bs[128 * 72];   // [n][k]

    const int tid = threadIdx.x;
    const int lane = tid & 63;
    const int wv = tid >> 6;         // wave -> 32-col slice
    const int row0 = blockIdx.x * 32;

    // A staging: thread -> row ar, k-segment ak (8 floats -> 8 bf16)
    const int ar = tid >> 3;         // 0..31
    const int ak = (tid & 7) * 8;    // 0..56
    const float* Ap = A + (size_t)(row0 + ar) * Mm + ak;

    // B staging: thread -> n-row bn, k-segment bk (32 bf16 = 4 x short8)
    const int bn = tid >> 1;         // 0..127
    const int bk = (tid & 1) * 32;
    const short* Bp = Bt + (size_t)bn * Mm + bk;

    const int fm = lane & 15;        // fragment row/col
    const int fk = (lane >> 4) * 8;  // fragment k offset

    float4v acc[2][2] = {};

    // 4 named prefetch register sets (no runtime indexing - rule #20)
    float4 a0A, a1A, a0B, a1B, a0C, a1C, a0D, a1D;
    short8v b0A, b1A, b2A, b3A, b0B, b1B, b2B, b3B;
    short8v b0C, b1C, b2C, b3C, b0D, b1D, b2D, b3D;

#define LOADSET(s, koff)                                   \
    a0##s = *(const float4*)(Ap + (koff));                 \
    a1##s = *(const float4*)(Ap + (koff) + 4);             \
    b0##s = *(const short8v*)(Bp + (koff));                \
    b1##s = *(const short8v*)(Bp + (koff) + 8);            \
    b2##s = *(const short8v*)(Bp + (koff) + 16);           \
    b3##s = *(const short8v*)(Bp + (koff) + 24);

#define PHASE(s, knext)                                                        \
    {                                                                          \
        short8v ap;                                                            \
        ap[0] = f2bf(a0##s.x); ap[1] = f2bf(a0##s.y);                          \
        ap[2] = f2bf(a0##s.z); ap[3] = f2bf(a0##s.w);                          \
        ap[4] = f2bf(a1##s.x); ap[5] = f2bf(a1##s.y);                          \
        ap[6] = f2bf(a1##s.z); ap[7] = f2bf(a1##s.w);                          \
        __builtin_amdgcn_sched_barrier(0);                                     \
        __builtin_amdgcn_s_barrier();       /* WAR: prev phase reads done */   \
        __builtin_amdgcn_sched_barrier(0);                                     \
        *(short8v*)(&As[ar * 72 + ak]) = ap;                                   \
        *(short8v*)(&Bs[bn * 72 + bk +  0]) = b0##s;                           \
        *(short8v*)(&Bs[bn * 72 + bk +  8]) = b1##s;                           \
        *(short8v*)(&Bs[bn * 72 + bk + 16]) = b2##s;                           \
        *(short8v*)(&Bs[bn * 72 + bk + 24]) = b3##s;                           \
        if ((knext) < Mm) { LOADSET(s, knext) }   /* prefetch 4 phases ahead */\
        asm volatile("s_waitcnt lgkmcnt(0)" ::: "memory");                     \
        __builtin_amdgcn_sched_barrier(0);                                     \
        __builtin_amdgcn_s_barrier();       /* RAW: writes visible */          \
        __builtin_amdgcn_sched_barrier(0);                                     \
        _Pragma("unroll")                                                      \
        for (int ks = 0; ks < 2; ks++) {                                       \
            const int kk = ks * 32 + fk;                                       \
            short8v a0f = *(const short8v*)(&As[fm * 72 + kk]);                \
            short8v a1f = *(const short8v*)(&As[(16 + fm) * 72 + kk]);         \
            short8v b0f = *(const short8v*)(&Bs[(wv * 32 + fm) * 72 + kk]);    \
            short8v b1f = *(const short8v*)(&Bs[(wv * 32 + 16 + fm) * 72 + kk]); \
            acc[0][0] = __builtin_amdgcn_mfma_f32_16x16x32_bf16(a0f, b0f, acc[0][0], 0, 0, 0); \
            acc[0][1] = __builtin_amdgcn_mfma_f32_16x16x32_bf16(a0f, b1f, acc[0][1], 0, 0, 0); \
            acc[1][0] = __builtin_amdgcn_mfma_f32_16x16x32_bf16(a1f, b0f, acc[1][0], 0, 0, 0); \
            acc[1][1] = __builtin_amdgcn_mfma_f32_16x16x32_bf16(a1f, b1f, acc[1][1], 0, 0, 0); \
        }                                                                      \
    }

    LOADSET(A, 0)        // chunk 0
    LOADSET(B, 64)       // chunk 1
    LOADSET(C, 128)      // chunk 2
    LOADSET(D, 192)      // chunk 3

    for (int k0 = 0; k0 < Mm; k0 += 256) {   // 32 iters x 4 phases = 128 chunks
        PHASE(A, k0 + 256)
        PHASE(B, k0 + 320)
        PHASE(C, k0 + 384)
        PHASE(D, k0 + 448)
    }
#undef PHASE
#undef LOADSET

    const int crow = (lane >> 4) * 4;
#pragma unroll
    for (int mt = 0; mt < 2; mt++)
#pragma unroll
        for (int nt = 0; nt < 2; nt++)
#pragma unroll
            for (int r = 0; r < 4; r++)
                C[(size_t)(row0 + mt * 16 + crow + r) * 128 + wv * 32 + nt * 16 + fm] =
                    acc[mt][nt][r];
}

// ---------------------------------------------------------------------------
// Zs = diag(rs_out) * ([curr_h | fused] @ Wp)    (16384 x 128, f32)
// Associativity: S*(X@Wp) == (S*X)@Wp -- do the dense matmul FIRST so the
// edge gather moves 512B rows instead of 1KB (halves gather traffic) and
// rs_out folds into Zs (no dependent scale-load in the gather chain).
// 32-row tile, 256 thr; thread (ty,tx) owns rows ty*4..+3, cols tx*4..+3.
// ---------------------------------------------------------------------------
__launch_bounds__(256, 2)
__global__ void k_gemmZ(const float* __restrict__ x1, const float* __restrict__ x2,
                        const float* __restrict__ B, const float* __restrict__ rs_o,
                        float* __restrict__ Zs) {
    __shared__ float As[32 * 36];
    __shared__ float Bs[32 * 128];

    const int tid = threadIdx.x;
    const int tx = tid & 31;
    const int ty = tid >> 5;
    const int c4 = tx * 4;
    const int r0 = ty * 4;
    const int row0 = blockIdx.x * 32;

    const int ar = tid >> 3;
    const int ak = (tid & 7) * 4;

    float acc[4][4] = {};

    for (int k0 = 0; k0 < 256; k0 += 32) {
        const float* src = (k0 < 128)
            ? x1 + (size_t)(row0 + ar) * 128 + k0 + ak
            : x2 + (size_t)(row0 + ar) * 128 + (k0 - 128) + ak;
        float4 av = *(const float4*)src;
        float4 bv[4];
#pragma unroll
        for (int t = 0; t < 4; t++) {
            int idx = tid + t * 256;
            int br = idx >> 5, bc = (idx & 31) * 4;
            bv[t] = *(const float4*)(B + (size_t)(k0 + br) * 128 + bc);
        }
        __syncthreads();
        As[(ak + 0) * 36 + ar] = av.x;
        As[(ak + 1) * 36 + ar] = av.y;
        As[(ak + 2) * 36 + ar] = av.z;
        As[(ak + 3) * 36 + ar] = av.w;
#pragma unroll
        for (int t = 0; t < 4; t++) {
            int idx = tid + t * 256;
            int br = idx >> 5, bc = (idx & 31) * 4;
            *(float4*)(Bs + br * 128 + bc) = bv[t];
        }
        __syncthreads();
#pragma unroll
        for (int kk = 0; kk < 32; kk++) {
            float4 a4 = *(const float4*)(As + kk * 36 + r0);
            float4 b4 = *(const float4*)(Bs + kk * 128 + c4);
            float a[4] = {a4.x, a4.y, a4.z, a4.w};
            float b[4] = {b4.x, b4.y, b4.z, b4.w};
#pragma unroll
            for (int i = 0; i < 4; i++)
#pragma unroll
                for (int j = 0; j < 4; j++)
                    acc[i][j] = fmaf(a[i], b[j], acc[i][j]);
        }
    }

#pragma unroll
    for (int i = 0; i < 4; i++) {
        float ro = rs_o[row0 + r0 + i];
        float4 v = {acc[i][0] * ro, acc[i][1] * ro, acc[i][2] * ro, acc[i][3] * ro};
        *(float4*)(Zs + (size_t)(row0 + r0 + i) * 128 + c4) = v;
    }
}

// ---------------------------------------------------------------------------
// Gather-aggregate Zs rows through the graph + fused epilogue:
// v = (rs_in[d]*(sum_e Zs[src_e] + Zs[d]) + bp) * 0.5 -> LayerNorm -> ReLU.
// One wave per dst node; lane holds 2 features. LN reduce: shfl_xor 32..1.
// ---------------------------------------------------------------------------
__global__ void k_aggln(const float* __restrict__ Zs, const float* __restrict__ rs_i,
                        const int* __restrict__ row_start, const int* __restrict__ ebuf,
                        const float* __restrict__ bp, const float* __restrict__ gamma,
                        const float* __restrict__ beta, float* __restrict__ out) {
    int d = blockIdx.x * 4 + (threadIdx.x >> 6);
    int lane = threadIdx.x & 63;
    int c = lane * 2;
    int beg = row_start[d], end = row_start[d + 1];
    float ax = 0.f, ay = 0.f;
    int i = beg;
    for (; i + 3 < end; i += 4) {   // unroll 4 for load MLP
        int s0 = ebuf[i], s1 = ebuf[i + 1], s2 = ebuf[i + 2], s3 = ebuf[i + 3];
        float2 v0 = *(const float2*)(Zs + (size_t)s0 * 128 + c);
        float2 v1 = *(const float2*)(Zs + (size_t)s1 * 128 + c);
        float2 v2 = *(const float2*)(Zs + (size_t)s2 * 128 + c);
        float2 v3 = *(const float2*)(Zs + (size_t)s3 * 128 + c);
        ax += (v0.x + v1.x) + (v2.x + v3.x);
        ay += (v0.y + v1.y) + (v2.y + v3.y);
    }
    for (; i < end; ++i) {
        int s0 = ebuf[i];
        float2 v0 = *(const float2*)(Zs + (size_t)s0 * 128 + c);
        ax += v0.x;
        ay += v0.y;
    }
    float2 self = *(const float2*)(Zs + (size_t)d * 128 + c);
    float ri = rs_i[d];
    float2 bpv = *(const float2*)(bp + c);
    float vx = (ri * (ax + self.x) + bpv.x) * 0.5f;
    float vy = (ri * (ay + self.y) + bpv.y) * 0.5f;

    float s1 = vx + vy;
    float s2 = vx * vx + vy * vy;
#pragma unroll
    for (int m = 32; m >= 1; m >>= 1) {
        s1 += __shfl_xor(s1, m);
        s2 += __shfl_xor(s2, m);
    }
    float mu  = s1 * (1.0f / 128.0f);
    float var = s2 * (1.0f / 128.0f) - mu * mu;
    float inv = rsqrtf(var + 1e-5f);
    float2 g = *(const float2*)(gamma + c);
    float2 b = *(const float2*)(beta + c);
    float2 o;
    o.x = fmaxf((vx - mu) * inv * g.x + b.x, 0.0f);
    o.y = fmaxf((vy - mu) * inv * g.y + b.y, 0.0f);
    *(float2*)(out + (size_t)d * 128 + c) = o;
}

// ---------------------------------------------------------------------------
extern "C" void kernel_launch(void* const* d_in, const int* in_sizes, int n_in,
                              void* d_out, int out_size, void* d_ws, size_t ws_size,
                              hipStream_t stream) {
    const float* curr_h    = (const float*)d_in[0];
    const float* next_h    = (const float*)d_in[1];
    const float* curr_inc  = (const float*)d_in[2];
    const float* Wc        = (const float*)d_in[3];
    const float* bc        = (const float*)d_in[4];
    const float* Wf        = (const float*)d_in[5];
    const float* bf        = (const float*)d_in[6];
    const float* conv_w    = (const float*)d_in[7];
    const float* topDown_w = (const float*)d_in[8];
    const float* gamma     = (const float*)d_in[9];
    const float* beta      = (const float*)d_in[10];
    const int*   esrc      = (const int*)d_in[11];
    const int*   edst      = (const int*)d_in[12];
    float* out = (float*)d_out;

    // workspace layout (~21 MB)
    char* w = (char*)d_ws;
    int*   cnt_out = (int*)w;    w += (size_t)Nn * 4;
    int*   cnt_in  = (int*)w;    w += (size_t)Nn * 4;
    int*   cursor  = (int*)w;    w += (size_t)Nn * 4;
    int*   row_st  = (int*)w;    w += (size_t)16388 * 4;
    int*   ebuf    = (int*)w;    w += (size_t)Ee * 4;
    float* rs_out  = (float*)w;  w += (size_t)Nn * 4;
    float* rs_in   = (float*)w;  w += (size_t)Nn * 4;
    short* Bt      = (short*)w;  w += (size_t)Dd * Mm * 2;
    float* fused   = (float*)w;  w += (size_t)Nn * Dd * 4;
    float* Zs      = (float*)w;  w += (size_t)Nn * Dd * 4;
    float* Wp      = (float*)w;  w += (size_t)256 * 128 * 4;
    float* bp      = (float*)w;  w += (size_t)1024;

    // CSR + degrees + weight prep (independent of big GEMM)
    k_zero_i<<<(3 * Nn + 255) / 256, 256, 0, stream>>>(cnt_out, 3 * Nn); // cnt_out,cnt_in,cursor contiguous
    k_deg_count<<<Ee / 256, 256, 0, stream>>>(esrc, edst, cnt_out, cnt_in);
    k_deg_fin<<<Nn / 256, 256, 0, stream>>>(cnt_out, cnt_in, rs_out, rs_in);
    k_scan<<<1, 1024, 0, stream>>>(cnt_in, row_st);
    k_fill<<<Ee / 256, 256, 0, stream>>>(esrc, edst, row_st, cursor, ebuf);
    k_prep<<<128, 256, 0, stream>>>(Wc, Wf, bc, bf, conv_w, topDown_w, Wp, bp);

    // B^T bf16, then big MFMA GEMM: fused = curr_inc @ next_h
    k_bt<<<1024, 256, 0, stream>>>(next_h, Bt);
    k_mfma_gemm<<<Nn / 32, 256, 0, stream>>>(curr_inc, Bt, fused);

    // dense matmul first (associativity), then one gather pass with LN fused
    k_gemmZ<<<Nn / 32, 256, 0, stream>>>(curr_h, fused, Wp, rs_out, Zs);
    k_aggln<<<Nn / 4, 256, 0, stream>>>(Zs, rs_in, row_st, ebuf, bp, gamma, beta, out);
}